// Round 13
// baseline (239.355 us; speedup 1.0000x reference)
//
#include <hip/hip_runtime.h>
#include <hip/hip_bf16.h>

// Problem constants
#define BATCH   2048
#define HW      81          // 9x9
#define CIN     39
#define NPIX    (BATCH*HW)  // 165888

// ws layout (float offsets)
#define WS_H1     0              // 10,616,832 floats  (B,64,81)  PRE-BN h
#define WS_MASK   10616832       // 1,492,992 floats   (B,9,81)
#define WS_WDT    12109824       // 36,864 ushort bf16 [k][o][c]   (18,432 floats)
#define WS_W1M    12128256       // 24,576 ushort bf16 [12][64][32] (12,288 floats)
#define WS_WCM    12140544       // 18,432 ushort bf16 [18][32][32] (9,216 floats)
#define WS_STATS  12149760       // 8192 floats: sum1[2048],sq1[2048],sum2[2048],sq2[2048]

#define OUT_OFF_BASE 1
#define OUT_H_BASE   (1 + BATCH*18*81)   // 2985985

typedef __attribute__((ext_vector_type(8))) short bfrag8;
typedef __attribute__((ext_vector_type(4))) float floatx4;

__device__ __forceinline__ unsigned short f2bf(float f) {
    unsigned u = __builtin_bit_cast(unsigned, f);
    u += 0x7FFFu + ((u >> 16) & 1u);       // round-to-nearest-even
    return (unsigned short)(u >> 16);
}
__device__ __forceinline__ float bfhi2f(unsigned hi16) {   // hi16 already in bits 31..16
    return __builtin_bit_cast(float, hi16);
}

// ---------------- weight prep: fragment-ready bf16 layouts --------------------
__global__ void prep_weights(const float* __restrict__ w1, const float* __restrict__ wo,
                             const float* __restrict__ wm, const float* __restrict__ wd,
                             float* __restrict__ ws) {
    int idx = blockIdx.x * 256 + threadIdx.x;
    unsigned short* w1m = (unsigned short*)(ws + WS_W1M);
    unsigned short* wcm = (unsigned short*)(ws + WS_WCM);
    unsigned short* wdt16 = (unsigned short*)(ws + WS_WDT);
    if (idx < 24576) {
        int kk = idx & 31, o = (idx >> 5) & 63, s = idx >> 11;
        int tap, c; bool ok = true;
        if (s < 9)       { tap = s;             c = kk; }
        else if (s == 9) { tap = kk >> 3;       c = 32 + (kk & 7); }
        else if (s == 10){ tap = 4 + (kk >> 3); c = 32 + (kk & 7); }
        else             { tap = 8;             c = 32 + (kk & 7); ok = (kk < 8); }
        float v = (ok && c < CIN) ? w1[(o * CIN + c) * 9 + tap] : 0.f;
        w1m[idx] = f2bf(v);
        return;
    }
    int j = idx - 24576;
    if (j >= 0 && j < 18432) {
        int kk = j & 31, oc = (j >> 5) & 31, s = j >> 10;
        int tap = s >> 1, c = (s & 1) * 32 + kk;
        float v = 0.f;
        if (oc < 18)      v = wo[(oc * 64 + c) * 9 + tap];
        else if (oc < 27) v = wm[((oc - 18) * 64 + c) * 9 + tap];
        wcm[j] = f2bf(v);
        return;
    }
    int m = idx - 24576 - 18432;
    if (m >= 0 && m < 36864) {
        int c = m & 63, o = (m >> 6) & 63, k = m >> 12;
        wdt16[m] = f2bf(wd[(o * 64 + c) * 9 + k]);
    }
}

// ---------------- conv1 (39->64) MFMA + ReLU + BN1 stats ----------------------
__global__ __launch_bounds__(256, 4) void conv1_mfma(
        const float* __restrict__ xg, const float* __restrict__ b1,
        const unsigned short* __restrict__ w1m, float* __restrict__ h1,
        float* __restrict__ sum1, float* __restrict__ sq1) {
    __shared__ short xs[128 * 64];   // [r(121)][c(64)] bf16, byte ^= (r&7)<<4
    int b = blockIdx.x, t = threadIdx.x;
    for (int i = t; i < 4096; i += 256) ((unsigned*)xs)[i] = 0u;
    __syncthreads();
    const float* xb = xg + (size_t)b * (HW * CIN);
    const float4* xb4 = (const float4*)xb;
    for (int i4 = t; i4 < 789; i4 += 256) {
        float4 v = xb4[i4];
        float vv[4] = { v.x, v.y, v.z, v.w };
        int base = 4 * i4;
#pragma unroll
        for (int k = 0; k < 4; ++k) {
            int idx = base + k;
            int p = idx / 39, c = idx - 39 * p;
            int y = p / 9, xx = p - 9 * y;
            int r = (y + 1) * 11 + xx + 1;
            int byte = r * 128 + ((c * 2) ^ ((r & 7) << 4));
            xs[byte >> 1] = (short)f2bf(vv[k]);
        }
    }
    if (t < 3) {
        int idx = 3156 + t;
        int p = idx / 39, c = idx - 39 * p;
        int y = p / 9, xx = p - 9 * y;
        int r = (y + 1) * 11 + xx + 1;
        int byte = r * 128 + ((c * 2) ^ ((r & 7) << 4));
        xs[byte >> 1] = (short)f2bf(xb[idx]);
    }
    __syncthreads();
    int lane = t & 63, wv = t >> 6, lg = lane >> 4, lr = lane & 15;
    int o = wv * 16 + lr;
    floatx4 acc[6];
#pragma unroll
    for (int n = 0; n < 6; ++n) acc[n] = (floatx4)0.f;
    int rbn[6];
#pragma unroll
    for (int n = 0; n < 6; ++n) {
        int p = n * 16 + lr; p = p > 80 ? 80 : p;
        int y = p / 9, xx = p - 9 * y;
        rbn[n] = (y + 1) * 11 + xx + 1;
    }
#pragma unroll
    for (int s = 0; s < 12; ++s) {
        bfrag8 a = *(const bfrag8*)&w1m[(s * 64 + o) * 32 + lg * 8];
        int roff, cb;
        if (s < 9)       { roff = (s / 3 - 1) * 11 + (s % 3) - 1; cb = lg * 16; }
        else if (s == 9) { roff = (lg / 3 - 1) * 11 + (lg % 3) - 1; cb = 64; }
        else if (s == 10){ int tp = lg + 4; roff = (tp / 3 - 1) * 11 + (tp % 3) - 1; cb = 64; }
        else             { roff = 12; cb = 64; }
#pragma unroll
        for (int n = 0; n < 6; ++n) {
            int r = rbn[n] + roff;
            int byte = r * 128 + (cb ^ ((r & 7) << 4));
            bfrag8 bf = *(const bfrag8*)((const char*)xs + byte);
            acc[n] = __builtin_amdgcn_mfma_f32_16x16x32_bf16(a, bf, acc[n], 0, 0, 0);
        }
    }
    float* h1b = h1 + (size_t)b * 5184;
    int bucket = (b & 31) << 6;
#pragma unroll
    for (int j = 0; j < 4; ++j) {
        int oo = wv * 16 + lg * 4 + j;
        float bias = b1[oo];
        float ss = 0.f, qq = 0.f;
#pragma unroll
        for (int n = 0; n < 6; ++n) {
            int p = n * 16 + lr;
            float v = fmaxf(acc[n][j] + bias, 0.f);
            if (p < 81) { h1b[oo * 81 + p] = v; ss += v; qq += v * v; }
        }
#pragma unroll
        for (int off = 1; off < 16; off <<= 1) { ss += __shfl_xor(ss, off); qq += __shfl_xor(qq, off); }
        if (lr == 0) { atomicAdd(&sum1[bucket + oo], ss); atomicAdd(&sq1[bucket + oo], qq); }
    }
}

// ---------------- BN2 finalize + apply (fused; aligned float4 body) -----------
__global__ __launch_bounds__(256) void bn_apply2(
        float* __restrict__ data, const float* __restrict__ sums,
        const float* __restrict__ sqs, const float* __restrict__ gamma,
        const float* __restrict__ beta, int n, float* __restrict__ dout) {
    __shared__ float sc[64], sh[64];
    int t = threadIdx.x;
    if (t < 64) {
        float s = 0.f, q = 0.f;
#pragma unroll
        for (int r = 0; r < 32; ++r) { s += sums[(r << 6) + t]; q += sqs[(r << 6) + t]; }
        float m = s / (float)NPIX;
        float v = q / (float)NPIX - m * m;
        float scv = gamma[t] * (1.f / sqrtf(v + 1e-5f));
        sc[t] = scv; sh[t] = beta[t] - m * scv;
    }
    __syncthreads();
    if (blockIdx.x == 0) {
        if (t == 0) dout[0] = 0.5f;
        if (t < 3) data[t] = data[t] * sc[0] + sh[0];   // e<81 -> c=0
        if (t == 3) {
            int e = n - 1;
            int c = (e / 81) & 63;
            data[e] = data[e] * sc[c] + sh[c];
        }
    }
    float4* d4 = (float4*)(data + 3);
    int n4 = (n - 4) >> 2;    // covers elements 3 .. n-2
    for (int i = blockIdx.x * 256 + t; i < n4; i += gridDim.x * 256) {
        float4 v = d4[i];
        unsigned e = 3u + 4u * (unsigned)i;
        int c0 = (int)((e) / 81u) & 63;
        int c1 = (int)((e + 1) / 81u) & 63;
        int c2 = (int)((e + 2) / 81u) & 63;
        int c3 = (int)((e + 3) / 81u) & 63;
        v.x = v.x * sc[c0] + sh[c0];
        v.y = v.y * sc[c1] + sh[c1];
        v.z = v.z * sc[c2] + sh[c2];
        v.w = v.w * sc[c3] + sh[c3];
        d4[i] = v;
    }
}

// ---------------- bilinear param helper ---------------------------------------
__device__ __forceinline__ void dcn_param(
        int item, int wv, const float* __restrict__ goff,
        const float* __restrict__ gmsk, uint2& rw, unsigned& rx) {
    int k = item >> 4, rloc = item & 15;
    int p = wv * 16 + rloc; p = p > 80 ? 80 : p;
    float dy = goff[(2 * k) * 81 + p];
    float dx = goff[(2 * k + 1) * 81 + p];
    float m  = gmsk[k * 81 + p];
    int y = p / 9, xx = p - y * 9;
    float py = dy + (float)(y + k / 3 - 1);
    float px = dx + (float)(xx + (k % 3) - 1);
    float fy = floorf(py), fx = floorf(px);
    float ly = py - fy, lx = px - fx;
    int y0 = (int)fy, x0 = (int)fx;
    int y1 = y0 + 1, x1 = x0 + 1;
    bool vy0 = (y0 >= 0) & (y0 < 9), vy1 = (y1 >= 0) & (y1 < 9);
    bool vx0 = (x0 >= 0) & (x0 < 9), vx1 = (x1 >= 0) & (x1 < 9);
    float w00 = (vy0 && vx0) ? m * (1.f - ly) * (1.f - lx) : 0.f;
    float w01 = (vy0 && vx1) ? m * (1.f - ly) * lx : 0.f;
    float w10 = (vy1 && vx0) ? m * ly * (1.f - lx) : 0.f;
    float w11 = (vy1 && vx1) ? m * ly * lx : 0.f;
    int yc0 = min(max(y0, 0), 8), yc1 = min(max(y1, 0), 8);
    int xc0 = min(max(x0, 0), 8), xc1 = min(max(x1, 0), 8);
    unsigned q00 = yc0 * 9 + xc0, q01 = yc0 * 9 + xc1;
    unsigned q10 = yc1 * 9 + xc0, q11 = yc1 * 9 + xc1;
    rw = make_uint2((unsigned)f2bf(w00) | ((unsigned)f2bf(w01) << 16),
                    (unsigned)f2bf(w10) | ((unsigned)f2bf(w11) << 16));
    rx = q00 | (q01 << 8) | (q10 << 16) | (q11 << 24);
}

// ---------------- FUSED offset/mask + deform conv: wave-private p-tiles -------
// 384 threads = 6 waves; wave wv owns pixels [wv*16, wv*16+16).
// LDS 33536B -> high occupancy:
//   hsh [0,20736)       f32 [q][256B], byte q*256 + ((c*4)^((q&15)<<4))
//   R   [20736,33024)   P0/P1: xs bf16 [r(82)][128B] byte r*128+((c*2)^((r&7)<<4))
//                       GEMM: 6 wave-private vt slices of 2048B (16 rows x 128B)
//   sc1/sh1 [33024,33536)
// Barriers: 3 total (sc1, post-P0, post-P1). GEMM phase is barrier-free:
// per-wave fill->MFMA in its private slice (DS ops are in-order per wave).
// Bilinear params live in registers (3 named slots/lane), distributed per tap
// via ds_bpermute (source slot k>>2 is compile-time in the unrolled loop).
__global__ __launch_bounds__(384, 5) void offdeform_mfma(
        const float* __restrict__ h1, const unsigned short* __restrict__ wcm,
        const unsigned short* __restrict__ wdt16,
        const float* __restrict__ bo, const float* __restrict__ bm,
        const float* __restrict__ bd,
        const float* __restrict__ sum1, const float* __restrict__ sq1,
        const float* __restrict__ g1, const float* __restrict__ be1,
        float* __restrict__ dout, float* __restrict__ maskb,
        float* __restrict__ sum2, float* __restrict__ sq2) {
    __shared__ __align__(16) char L[33536];
    float* hsh = (float*)L;
    char*  xs  = L + 20736;
    float* sc1 = (float*)(L + 33024);
    float* sh1 = (float*)(L + 33280);

    int b = blockIdx.x, t = threadIdx.x;
    int lane = t & 63, wv = t >> 6, lg = lane >> 4, lr = lane & 15;

    // ---- BN1 finalize folded in
    if (t < 64) {
        float s = 0.f, q = 0.f;
#pragma unroll
        for (int r = 0; r < 32; ++r) { s += sum1[(r << 6) + t]; q += sq1[(r << 6) + t]; }
        float m = s / (float)NPIX;
        float v = q / (float)NPIX - m * m;
        float scv = g1[t] * (1.f / sqrtf(v + 1e-5f));
        sc1[t] = scv; sh1[t] = be1[t] - m * scv;
    }
    __syncthreads();                                   // barrier 1

    // ---- P0: stage hsh (f32 swizzled) + xs (bf16 vt-layout), BN1 folded
    const float* hb = h1 + (size_t)b * 5184;
    for (int i = t; i < 2592; i += 384) {
        int c2 = i / 81, q = i - c2 * 81;
        int c = 2 * c2;
        float va = hb[c * 81 + q]      * sc1[c]     + sh1[c];
        float vb = hb[c * 81 + 81 + q] * sc1[c + 1] + sh1[c + 1];
        *(float2*)((char*)hsh + q * 256 + ((c * 4) ^ ((q & 15) << 4))) = make_float2(va, vb);
        unsigned pk;
        asm("v_cvt_pk_bf16_f32 %0, %1, %2" : "=v"(pk) : "v"(va), "v"(vb));
        *(unsigned*)(xs + q * 128 + ((c * 2) ^ ((q & 7) << 4))) = pk;
    }
    if (t < 32) *(unsigned*)(xs + 81 * 128 + t * 4) = 0u;   // zero row 81
    __syncthreads();                                   // barrier 2

    // ---- P1: wave-private p-tile offset/mask GEMM (both oc-tiles)
    int p0 = wv * 16 + lr;
    int pc = p0 > 80 ? 80 : p0;
    int yy0 = pc / 9, xx0 = pc - 9 * yy0;
    floatx4 oacc0 = (floatx4)0.f, oacc1 = (floatx4)0.f;
#pragma unroll
    for (int s = 0; s < 18; ++s) {
        const int tap = s >> 1, dyk = tap / 3 - 1, dxk = tap % 3 - 1;
        const int cb1 = (s & 1) * 64 + lg * 16;
        bfrag8 a0 = *(const bfrag8*)&wcm[(s * 32 + lr) * 32 + lg * 8];
        bfrag8 a1 = *(const bfrag8*)&wcm[(s * 32 + 16 + lr) * 32 + lg * 8];
        int yy = yy0 + dyk, xx2 = xx0 + dxk;
        bool val = ((unsigned)yy < 9u) & ((unsigned)xx2 < 9u);
        int q2 = val ? yy * 9 + xx2 : 81;
        bfrag8 bf = *(const bfrag8*)(xs + q2 * 128 + (cb1 ^ ((q2 & 7) << 4)));
        oacc0 = __builtin_amdgcn_mfma_f32_16x16x32_bf16(a0, bf, oacc0, 0, 0, 0);
        oacc1 = __builtin_amdgcn_mfma_f32_16x16x32_bf16(a1, bf, oacc1, 0, 0, 0);
    }
    // P1 epilogue: offsets -> dout (program output), mask -> maskb (global)
    if (p0 < 81) {
        float* ob = dout + OUT_OFF_BASE + (size_t)b * 1458;
        float* mb = maskb + (size_t)b * 729;
#pragma unroll
        for (int j = 0; j < 4; ++j) {
            int oc = lg * 4 + j;                       // mt=0: oc 0..15 (offsets)
            ob[oc * 81 + p0] = oacc0[j] + bo[oc];
            int oc2 = 16 + lg * 4 + j;                 // mt=1: oc 16..31
            float v = oacc1[j];
            if (oc2 < 18) ob[oc2 * 81 + p0] = v + bo[oc2];
            else if (oc2 < 27) {
                float vv = v + bm[oc2 - 18];
                mb[(oc2 - 18) * 81 + p0] = 1.f / (1.f + expf(-vv));
            }
        }
    }
    __syncthreads();                                   // barrier 3 (xs dead; vmcnt drained)

    // ---- P2: wave-local bilinear params into 3 named register slots
    const float* goff = dout + OUT_OFF_BASE + (size_t)b * 1458;
    const float* gmsk = maskb + (size_t)b * 729;
    uint2 pw0, pw1, pw2 = make_uint2(0u, 0u);
    unsigned px0, px1, px2 = 0u;
    dcn_param(lane, wv, goff, gmsk, pw0, px0);
    dcn_param(lane + 64, wv, goff, gmsk, pw1, px1);
    if (lane < 16) dcn_param(lane + 128, wv, goff, gmsk, pw2, px2);

    // ---- GEMM phase: barrier-free, wave-private slice
    char* slice = L + 20736 + wv * 2048;
    const char* hc = (const char*)L;
    floatx4 acc[4];
#pragma unroll
    for (int n = 0; n < 4; ++n) acc[n] = (floatx4)0.f;
    int g = lane & 3, rloc = lane >> 2;
    int srcb = (((0) & 3) * 16 + rloc) << 2;           // recomputed per k below

#pragma unroll
    for (int k = 0; k < 9; ++k) {
        // A fragments for this tap (global, L1/L2-hot) — issue early
        bfrag8 A0 = *(const bfrag8*)&wdt16[(k * 64 + lr) * 64 + lg * 8];
        bfrag8 A1 = *(const bfrag8*)&wdt16[(k * 64 + lr) * 64 + 32 + lg * 8];
        bfrag8 A2 = *(const bfrag8*)&wdt16[(k * 64 + 16 + lr) * 64 + lg * 8];
        bfrag8 A3 = *(const bfrag8*)&wdt16[(k * 64 + 16 + lr) * 64 + 32 + lg * 8];
        bfrag8 A4 = *(const bfrag8*)&wdt16[(k * 64 + 32 + lr) * 64 + lg * 8];
        bfrag8 A5 = *(const bfrag8*)&wdt16[(k * 64 + 32 + lr) * 64 + 32 + lg * 8];
        bfrag8 A6 = *(const bfrag8*)&wdt16[(k * 64 + 48 + lr) * 64 + lg * 8];
        bfrag8 A7 = *(const bfrag8*)&wdt16[(k * 64 + 48 + lr) * 64 + 32 + lg * 8];

        // distribute this tap's param to the 4 g-lanes of each row
        srcb = (((k & 3) * 16) + rloc) << 2;
        unsigned bwx, bwy, bixv;
        if (k < 4) {
            bwx = (unsigned)__builtin_amdgcn_ds_bpermute(srcb, (int)pw0.x);
            bwy = (unsigned)__builtin_amdgcn_ds_bpermute(srcb, (int)pw0.y);
            bixv = (unsigned)__builtin_amdgcn_ds_bpermute(srcb, (int)px0);
        } else if (k < 8) {
            bwx = (unsigned)__builtin_amdgcn_ds_bpermute(srcb, (int)pw1.x);
            bwy = (unsigned)__builtin_amdgcn_ds_bpermute(srcb, (int)pw1.y);
            bixv = (unsigned)__builtin_amdgcn_ds_bpermute(srcb, (int)px1);
        } else {
            bwx = (unsigned)__builtin_amdgcn_ds_bpermute(srcb, (int)pw2.x);
            bwy = (unsigned)__builtin_amdgcn_ds_bpermute(srcb, (int)pw2.y);
            bixv = (unsigned)__builtin_amdgcn_ds_bpermute(srcb, (int)px2);
        }
        float w00 = bfhi2f(bwx << 16), w01 = bfhi2f(bwx & 0xffff0000u);
        float w10 = bfhi2f(bwy << 16), w11 = bfhi2f(bwy & 0xffff0000u);
        unsigned q00 = bixv & 255u, q01 = (bixv >> 8) & 255u;
        unsigned q10 = (bixv >> 16) & 255u, q11 = bixv >> 24;
        int b00 = (int)((q00 << 8) | ((q00 & 15u) << 4));
        int b01 = (int)((q01 << 8) | ((q01 & 15u) << 4));
        int b10 = (int)((q10 << 8) | ((q10 & 15u) << 4));
        int b11 = (int)((q11 << 8) | ((q11 & 15u) << 4));
        int gb = g * 64;
        unsigned res[8];
#pragma unroll
        for (int jj = 0; jj < 4; ++jj) {
            int off = gb + jj * 16;
            floatx4 a4 = *(const floatx4*)(hc + (b00 ^ off)) * w00;
            a4 += *(const floatx4*)(hc + (b01 ^ off)) * w01;
            a4 += *(const floatx4*)(hc + (b10 ^ off)) * w10;
            a4 += *(const floatx4*)(hc + (b11 ^ off)) * w11;
            unsigned pk0, pk1;
            asm("v_cvt_pk_bf16_f32 %0, %1, %2" : "=v"(pk0) : "v"(a4.x), "v"(a4.y));
            asm("v_cvt_pk_bf16_f32 %0, %1, %2" : "=v"(pk1) : "v"(a4.z), "v"(a4.w));
            res[2 * jj] = pk0; res[2 * jj + 1] = pk1;
        }
        int swzv = (rloc & 7) << 4;
        char* row = slice + rloc * 128;
        *(uint4*)(row + ((32 * g) ^ swzv)) = make_uint4(res[0], res[1], res[2], res[3]);
        *(uint4*)(row + ((32 * g + 16) ^ swzv)) = make_uint4(res[4], res[5], res[6], res[7]);

        // B fragments from own slice (in-order DS within wave; no barrier)
        int swzr = (lr & 7) << 4;
        bfrag8 B0 = *(const bfrag8*)(slice + lr * 128 + ((lg * 16) ^ swzr));
        bfrag8 B1 = *(const bfrag8*)(slice + lr * 128 + ((64 + lg * 16) ^ swzr));
        acc[0] = __builtin_amdgcn_mfma_f32_16x16x32_bf16(A0, B0, acc[0], 0, 0, 0);
        acc[0] = __builtin_amdgcn_mfma_f32_16x16x32_bf16(A1, B1, acc[0], 0, 0, 0);
        acc[1] = __builtin_amdgcn_mfma_f32_16x16x32_bf16(A2, B0, acc[1], 0, 0, 0);
        acc[1] = __builtin_amdgcn_mfma_f32_16x16x32_bf16(A3, B1, acc[1], 0, 0, 0);
        acc[2] = __builtin_amdgcn_mfma_f32_16x16x32_bf16(A4, B0, acc[2], 0, 0, 0);
        acc[2] = __builtin_amdgcn_mfma_f32_16x16x32_bf16(A5, B1, acc[2], 0, 0, 0);
        acc[3] = __builtin_amdgcn_mfma_f32_16x16x32_bf16(A6, B0, acc[3], 0, 0, 0);
        acc[3] = __builtin_amdgcn_mfma_f32_16x16x32_bf16(A7, B1, acc[3], 0, 0, 0);
    }

    // ---- epilogue: bias, pre-BN output, BN2 stats (replicated buckets)
    float* outb = dout + OUT_H_BASE + (size_t)b * 5184;
    int bucket = (b & 31) << 6;
    bool pval = p0 < 81;
#pragma unroll
    for (int mt = 0; mt < 4; ++mt) {
#pragma unroll
        for (int j = 0; j < 4; ++j) {
            int o = mt * 16 + lg * 4 + j;
            float v = acc[mt][j] + bd[o];
            float ss = 0.f, qq = 0.f;
            if (pval) { outb[o * 81 + p0] = v; ss = v; qq = v * v; }
#pragma unroll
            for (int off = 1; off < 16; off <<= 1) {
                ss += __shfl_xor(ss, off);
                qq += __shfl_xor(qq, off);
            }
            if (lr == 0) { atomicAdd(&sum2[bucket + o], ss); atomicAdd(&sq2[bucket + o], qq); }
        }
    }
}

// ---------------- launch -------------------------------------------------------
extern "C" void kernel_launch(void* const* d_in, const int* in_sizes, int n_in,
                              void* d_out, int out_size, void* d_ws, size_t ws_size,
                              hipStream_t stream) {
    const float* x   = (const float*)d_in[0];
    const float* w1  = (const float*)d_in[1];
    const float* b1  = (const float*)d_in[2];
    const float* g1  = (const float*)d_in[3];
    const float* be1 = (const float*)d_in[4];
    const float* wo  = (const float*)d_in[5];
    const float* bo  = (const float*)d_in[6];
    const float* wm  = (const float*)d_in[7];
    const float* bm  = (const float*)d_in[8];
    const float* wd  = (const float*)d_in[9];
    const float* bd  = (const float*)d_in[10];
    const float* g2  = (const float*)d_in[11];
    const float* be2 = (const float*)d_in[12];
    float* dout = (float*)d_out;
    float* ws   = (float*)d_ws;

    float* h1    = ws + WS_H1;
    float* maskb = ws + WS_MASK;
    const unsigned short* wdt16 = (const unsigned short*)(ws + WS_WDT);
    const unsigned short* w1m   = (const unsigned short*)(ws + WS_W1M);
    const unsigned short* wcm   = (const unsigned short*)(ws + WS_WCM);
    float* stats = ws + WS_STATS;
    float* sum1 = stats,        *sq1 = stats + 2048;
    float* sum2 = stats + 4096, *sq2 = stats + 6144;

    // zero the replicated BN accumulators (ws is NOT re-poisoned between replays)
    hipMemsetAsync(stats, 0, 8192 * sizeof(float), stream);

    prep_weights<<<312, 256, 0, stream>>>(w1, wo, wm, wd, ws);
    conv1_mfma<<<BATCH, 256, 0, stream>>>(x, b1, w1m, h1, sum1, sq1);
    offdeform_mfma<<<BATCH, 384, 0, stream>>>(h1, wcm, wdt16, bo, bm, bd,
                                              sum1, sq1, g1, be1, dout, maskb, sum2, sq2);
    bn_apply2<<<2048, 256, 0, stream>>>(dout + OUT_H_BASE, sum2, sq2, g2, be2,
                                        BATCH * 5184, dout);
}

// Round 14
// 139.286 us; speedup vs baseline: 1.7184x; 1.7184x over previous
//
#include <hip/hip_runtime.h>
#include <hip/hip_bf16.h>

// Problem constants
#define BATCH   2048
#define HW      81          // 9x9
#define CIN     39
#define NPIX    (BATCH*HW)  // 165888

// ws layout (float offsets)
#define WS_H1     0              // 10,616,832 floats  (B,64,81)  PRE-BN h
#define WS_MASK   10616832       // 1,492,992 floats   (B,9,81)
#define WS_WDT    12109824       // 36,864 ushort bf16 [k][o][c]   (18,432 floats)
#define WS_W1M    12128256       // 24,576 ushort bf16 [12][64][32] (12,288 floats)
#define WS_WCM    12140544       // 18,432 ushort bf16 [18][32][32] (9,216 floats)
#define WS_STATS  12149760       // 8192 floats: sum1[2048],sq1[2048],sum2[2048],sq2[2048]

#define OUT_OFF_BASE 1
#define OUT_H_BASE   (1 + BATCH*18*81)   // 2985985

typedef __attribute__((ext_vector_type(8))) short bfrag8;
typedef __attribute__((ext_vector_type(4))) float floatx4;

__device__ __forceinline__ unsigned short f2bf(float f) {
    unsigned u = __builtin_bit_cast(unsigned, f);
    u += 0x7FFFu + ((u >> 16) & 1u);       // round-to-nearest-even
    return (unsigned short)(u >> 16);
}
__device__ __forceinline__ float bfhi2f(unsigned hi16) {   // hi16 already in bits 31..16
    return __builtin_bit_cast(float, hi16);
}

// ---------------- weight prep: fragment-ready bf16 layouts --------------------
__global__ void prep_weights(const float* __restrict__ w1, const float* __restrict__ wo,
                             const float* __restrict__ wm, const float* __restrict__ wd,
                             float* __restrict__ ws) {
    int idx = blockIdx.x * 256 + threadIdx.x;
    unsigned short* w1m = (unsigned short*)(ws + WS_W1M);
    unsigned short* wcm = (unsigned short*)(ws + WS_WCM);
    unsigned short* wdt16 = (unsigned short*)(ws + WS_WDT);
    if (idx < 24576) {
        int kk = idx & 31, o = (idx >> 5) & 63, s = idx >> 11;
        int tap, c; bool ok = true;
        if (s < 9)       { tap = s;             c = kk; }
        else if (s == 9) { tap = kk >> 3;       c = 32 + (kk & 7); }
        else if (s == 10){ tap = 4 + (kk >> 3); c = 32 + (kk & 7); }
        else             { tap = 8;             c = 32 + (kk & 7); ok = (kk < 8); }
        float v = (ok && c < CIN) ? w1[(o * CIN + c) * 9 + tap] : 0.f;
        w1m[idx] = f2bf(v);
        return;
    }
    int j = idx - 24576;
    if (j >= 0 && j < 18432) {
        int kk = j & 31, oc = (j >> 5) & 31, s = j >> 10;
        int tap = s >> 1, c = (s & 1) * 32 + kk;
        float v = 0.f;
        if (oc < 18)      v = wo[(oc * 64 + c) * 9 + tap];
        else if (oc < 27) v = wm[((oc - 18) * 64 + c) * 9 + tap];
        wcm[j] = f2bf(v);
        return;
    }
    int m = idx - 24576 - 18432;
    if (m >= 0 && m < 36864) {
        int c = m & 63, o = (m >> 6) & 63, k = m >> 12;
        wdt16[m] = f2bf(wd[(o * 64 + c) * 9 + k]);
    }
}

// ---------------- conv1 (39->64) MFMA + ReLU + BN1 stats ----------------------
__global__ __launch_bounds__(256, 4) void conv1_mfma(
        const float* __restrict__ xg, const float* __restrict__ b1,
        const unsigned short* __restrict__ w1m, float* __restrict__ h1,
        float* __restrict__ sum1, float* __restrict__ sq1) {
    __shared__ short xs[128 * 64];   // [r(121)][c(64)] bf16, byte ^= (r&7)<<4
    int b = blockIdx.x, t = threadIdx.x;
    for (int i = t; i < 4096; i += 256) ((unsigned*)xs)[i] = 0u;
    __syncthreads();
    const float* xb = xg + (size_t)b * (HW * CIN);
    const float4* xb4 = (const float4*)xb;
    for (int i4 = t; i4 < 789; i4 += 256) {
        float4 v = xb4[i4];
        float vv[4] = { v.x, v.y, v.z, v.w };
        int base = 4 * i4;
#pragma unroll
        for (int k = 0; k < 4; ++k) {
            int idx = base + k;
            int p = idx / 39, c = idx - 39 * p;
            int y = p / 9, xx = p - 9 * y;
            int r = (y + 1) * 11 + xx + 1;
            int byte = r * 128 + ((c * 2) ^ ((r & 7) << 4));
            xs[byte >> 1] = (short)f2bf(vv[k]);
        }
    }
    if (t < 3) {
        int idx = 3156 + t;
        int p = idx / 39, c = idx - 39 * p;
        int y = p / 9, xx = p - 9 * y;
        int r = (y + 1) * 11 + xx + 1;
        int byte = r * 128 + ((c * 2) ^ ((r & 7) << 4));
        xs[byte >> 1] = (short)f2bf(xb[idx]);
    }
    __syncthreads();
    int lane = t & 63, wv = t >> 6, lg = lane >> 4, lr = lane & 15;
    int o = wv * 16 + lr;
    floatx4 acc[6];
#pragma unroll
    for (int n = 0; n < 6; ++n) acc[n] = (floatx4)0.f;
    int rbn[6];
#pragma unroll
    for (int n = 0; n < 6; ++n) {
        int p = n * 16 + lr; p = p > 80 ? 80 : p;
        int y = p / 9, xx = p - 9 * y;
        rbn[n] = (y + 1) * 11 + xx + 1;
    }
#pragma unroll
    for (int s = 0; s < 12; ++s) {
        bfrag8 a = *(const bfrag8*)&w1m[(s * 64 + o) * 32 + lg * 8];
        int roff, cb;
        if (s < 9)       { roff = (s / 3 - 1) * 11 + (s % 3) - 1; cb = lg * 16; }
        else if (s == 9) { roff = (lg / 3 - 1) * 11 + (lg % 3) - 1; cb = 64; }
        else if (s == 10){ int tp = lg + 4; roff = (tp / 3 - 1) * 11 + (tp % 3) - 1; cb = 64; }
        else             { roff = 12; cb = 64; }
#pragma unroll
        for (int n = 0; n < 6; ++n) {
            int r = rbn[n] + roff;
            int byte = r * 128 + (cb ^ ((r & 7) << 4));
            bfrag8 bf = *(const bfrag8*)((const char*)xs + byte);
            acc[n] = __builtin_amdgcn_mfma_f32_16x16x32_bf16(a, bf, acc[n], 0, 0, 0);
        }
    }
    float* h1b = h1 + (size_t)b * 5184;
    int bucket = (b & 31) << 6;
#pragma unroll
    for (int j = 0; j < 4; ++j) {
        int oo = wv * 16 + lg * 4 + j;
        float bias = b1[oo];
        float ss = 0.f, qq = 0.f;
#pragma unroll
        for (int n = 0; n < 6; ++n) {
            int p = n * 16 + lr;
            float v = fmaxf(acc[n][j] + bias, 0.f);
            if (p < 81) { h1b[oo * 81 + p] = v; ss += v; qq += v * v; }
        }
#pragma unroll
        for (int off = 1; off < 16; off <<= 1) { ss += __shfl_xor(ss, off); qq += __shfl_xor(qq, off); }
        if (lr == 0) { atomicAdd(&sum1[bucket + oo], ss); atomicAdd(&sq1[bucket + oo], qq); }
    }
}

// ---------------- BN2 finalize + apply (fused; aligned float4 body) -----------
__global__ __launch_bounds__(256) void bn_apply2(
        float* __restrict__ data, const float* __restrict__ sums,
        const float* __restrict__ sqs, const float* __restrict__ gamma,
        const float* __restrict__ beta, int n, float* __restrict__ dout) {
    __shared__ float sc[64], sh[64];
    int t = threadIdx.x;
    if (t < 64) {
        float s = 0.f, q = 0.f;
#pragma unroll
        for (int r = 0; r < 32; ++r) { s += sums[(r << 6) + t]; q += sqs[(r << 6) + t]; }
        float m = s / (float)NPIX;
        float v = q / (float)NPIX - m * m;
        float scv = gamma[t] * (1.f / sqrtf(v + 1e-5f));
        sc[t] = scv; sh[t] = beta[t] - m * scv;
    }
    __syncthreads();
    if (blockIdx.x == 0) {
        if (t == 0) dout[0] = 0.5f;
        if (t < 3) data[t] = data[t] * sc[0] + sh[0];   // e<81 -> c=0
        if (t == 3) {
            int e = n - 1;
            int c = (e / 81) & 63;
            data[e] = data[e] * sc[c] + sh[c];
        }
    }
    float4* d4 = (float4*)(data + 3);
    int n4 = (n - 4) >> 2;    // covers elements 3 .. n-2
    for (int i = blockIdx.x * 256 + t; i < n4; i += gridDim.x * 256) {
        float4 v = d4[i];
        unsigned e = 3u + 4u * (unsigned)i;
        int c0 = (int)((e) / 81u) & 63;
        int c1 = (int)((e + 1) / 81u) & 63;
        int c2 = (int)((e + 2) / 81u) & 63;
        int c3 = (int)((e + 3) / 81u) & 63;
        v.x = v.x * sc[c0] + sh[c0];
        v.y = v.y * sc[c1] + sh[c1];
        v.z = v.z * sc[c2] + sh[c2];
        v.w = v.w * sc[c3] + sh[c3];
        d4[i] = v;
    }
}

// ---------------- FUSED offset/mask conv + deformable conv (MFMA) --------------
// r12 structure + fill compute/write split: tap k+1's interpolation is computed
// into registers DURING tap k's MFMA section (hsh/bwt/bix are read-only there);
// only the ds_writes sit between the barrier pair. Same arithmetic, same
// barrier count — the fill latency overlaps the MFMA phase per wave.
// LDS 40496B -> 4 blocks/CU:
//   hsh [0,20736)      f32 [q][256B], byte q*256 + ((c*4)^((q&15)<<4))
//   bwt [20736,26568)  uint2[729] packed bf16 bilinear weights
//   bix [26568,29484)  uint[729] 4x u8 corner q-indices
//   xs/vt [29488,39984) bf16 [r(82)][64c], byte r*128 + ((c*2)^((r&7)<<4));
//                       row 81 = zeros (P1 OOB fragments)
//   sc1/sh1 [39984,40496) BN1 scale/shift
__global__ __launch_bounds__(256, 4) void offdeform_mfma(
        const float* __restrict__ h1, const unsigned short* __restrict__ wcm,
        const unsigned short* __restrict__ wdt16,
        const float* __restrict__ bo, const float* __restrict__ bm,
        const float* __restrict__ bd,
        const float* __restrict__ sum1, const float* __restrict__ sq1,
        const float* __restrict__ g1, const float* __restrict__ be1,
        float* __restrict__ dout, float* __restrict__ maskb,
        float* __restrict__ sum2, float* __restrict__ sq2) {
    __shared__ __align__(16) char L[40496];
    float*    hsh = (float*)L;
    uint2*    bwt = (uint2*)(L + 20736);
    unsigned* bix = (unsigned*)(L + 26568);
    char*     vtb = L + 29488;               // xs during P0/P1, vt during fills
    float*    sc1 = (float*)(L + 39984);
    float*    sh1 = (float*)(L + 40240);

    int b = blockIdx.x, t = threadIdx.x;
    int lane = t & 63, wv = t >> 6, lg = lane >> 4, lr = lane & 15;

    // ---- BN1 finalize folded in (per block, cheap)
    if (t < 64) {
        float s = 0.f, q = 0.f;
#pragma unroll
        for (int r = 0; r < 32; ++r) { s += sum1[(r << 6) + t]; q += sq1[(r << 6) + t]; }
        float m = s / (float)NPIX;
        float v = q / (float)NPIX - m * m;
        float scv = g1[t] * (1.f / sqrtf(v + 1e-5f));
        sc1[t] = scv; sh1[t] = be1[t] - m * scv;
    }
    __syncthreads();

    // ---- P0: stage h as f32 hsh (swizzled) + bf16 xs (vt layout), BN1 folded
    const float* hb = h1 + (size_t)b * 5184;
    for (int i = t; i < 2592; i += 256) {
        int c2 = i / 81, q = i - c2 * 81;
        int c = 2 * c2;
        float va = hb[c * 81 + q]      * sc1[c]     + sh1[c];
        float vb = hb[c * 81 + 81 + q] * sc1[c + 1] + sh1[c + 1];
        *(float2*)((char*)hsh + q * 256 + ((c * 4) ^ ((q & 15) << 4))) = make_float2(va, vb);
        unsigned pk;
        asm("v_cvt_pk_bf16_f32 %0, %1, %2" : "=v"(pk) : "v"(va), "v"(vb));
        *(unsigned*)(vtb + q * 128 + ((c * 2) ^ ((q & 7) << 4))) = pk;
    }
    if (t < 32) *(unsigned*)(vtb + 81 * 128 + t * 4) = 0u;   // zero row 81
    __syncthreads();

    // ---- P1: offset/mask GEMM; OOB fragments -> zero row (no select)
    int mt = wv >> 1, nh = (wv & 1) * 3;
    int ocr = mt * 16 + lr;
    floatx4 oacc[3];
#pragma unroll
    for (int n = 0; n < 3; ++n) oacc[n] = (floatx4)0.f;
    int yn[3], xn[3];
#pragma unroll
    for (int ni = 0; ni < 3; ++ni) {
        int p = (nh + ni) * 16 + lr; p = p > 80 ? 80 : p;
        yn[ni] = p / 9; xn[ni] = p - 9 * yn[ni];
    }
#pragma unroll
    for (int s = 0; s < 18; ++s) {
        const int tap = s >> 1, dyk = tap / 3 - 1, dxk = tap % 3 - 1;
        const int cb1 = (s & 1) * 64 + lg * 16;
        bfrag8 af = *(const bfrag8*)&wcm[(s * 32 + ocr) * 32 + lg * 8];
#pragma unroll
        for (int ni = 0; ni < 3; ++ni) {
            int yy = yn[ni] + dyk, xx2 = xn[ni] + dxk;
            bool val = ((unsigned)yy < 9u) & ((unsigned)xx2 < 9u);
            int q2 = val ? yy * 9 + xx2 : 81;
            bfrag8 bf = *(const bfrag8*)(vtb + q2 * 128 + (cb1 ^ ((q2 & 7) << 4)));
            oacc[ni] = __builtin_amdgcn_mfma_f32_16x16x32_bf16(af, bf, oacc[ni], 0, 0, 0);
        }
    }
    // P1 epilogue: offsets -> dout (program output), mask -> maskb (global)
#pragma unroll
    for (int j = 0; j < 4; ++j) {
        int oc = mt * 16 + lg * 4 + j;
        if (oc < 18) {
            float bias = bo[oc];
            float* ob = dout + OUT_OFF_BASE + (size_t)b * 1458 + oc * 81;
#pragma unroll
            for (int ni = 0; ni < 3; ++ni) {
                int p = (nh + ni) * 16 + lr;
                if (p < 81) ob[p] = oacc[ni][j] + bias;
            }
        } else if (oc < 27) {
            float bias = bm[oc - 18];
            float* mb = maskb + (size_t)b * 729 + (oc - 18) * 81;
#pragma unroll
            for (int ni = 0; ni < 3; ++ni) {
                int p = (nh + ni) * 16 + lr;
                if (p < 81) { float v = oacc[ni][j] + bias; mb[p] = 1.f / (1.f + expf(-v)); }
            }
        }
    }
    __syncthreads();   // xs reads done; stores drained (vmcnt(0) before barrier)

    // ---- deform A fragments (L2-hot; latency hides under P2)
    int o = wv * 16 + lr;
    bfrag8 a[18];
#pragma unroll
    for (int s = 0; s < 18; ++s) {
        int k = s >> 1, ks = s & 1;
        a[s] = *(const bfrag8*)&wdt16[(k * 64 + o) * 64 + ks * 32 + lg * 8];
    }

    // ---- P2: bilinear params per (tap,pixel) from global offsets/mask
    const float* goff = dout + OUT_OFF_BASE + (size_t)b * 1458;
    const float* gmsk = maskb + (size_t)b * 729;
    for (int i = t; i < 729; i += 256) {
        int k = i / 81, p = i - k * 81;
        float dy = goff[(2 * k) * 81 + p];
        float dx = goff[(2 * k + 1) * 81 + p];
        float m  = gmsk[i];
        int y = p / 9, xx = p - y * 9;
        float py = dy + (float)(y + k / 3 - 1);
        float px = dx + (float)(xx + (k % 3) - 1);
        float fy = floorf(py), fx = floorf(px);
        float ly = py - fy, lx = px - fx;
        int y0 = (int)fy, x0 = (int)fx;
        int y1 = y0 + 1, x1 = x0 + 1;
        bool vy0 = (y0 >= 0) & (y0 < 9), vy1 = (y1 >= 0) & (y1 < 9);
        bool vx0 = (x0 >= 0) & (x0 < 9), vx1 = (x1 >= 0) & (x1 < 9);
        float w00 = (vy0 && vx0) ? m * (1.f - ly) * (1.f - lx) : 0.f;
        float w01 = (vy0 && vx1) ? m * (1.f - ly) * lx : 0.f;
        float w10 = (vy1 && vx0) ? m * ly * (1.f - lx) : 0.f;
        float w11 = (vy1 && vx1) ? m * ly * lx : 0.f;
        int yc0 = min(max(y0, 0), 8), yc1 = min(max(y1, 0), 8);
        int xc0 = min(max(x0, 0), 8), xc1 = min(max(x1, 0), 8);
        unsigned q00 = yc0 * 9 + xc0, q01 = yc0 * 9 + xc1;
        unsigned q10 = yc1 * 9 + xc0, q11 = yc1 * 9 + xc1;
        bwt[i] = make_uint2((unsigned)f2bf(w00) | ((unsigned)f2bf(w01) << 16),
                            (unsigned)f2bf(w10) | ((unsigned)f2bf(w11) << 16));
        bix[i] = q00 | (q01 << 8) | (q10 << 16) | (q11 << 24);
    }
    __syncthreads();   // xs dead; vt region free for fills; bwt/bix visible

    // ---- fill slot helpers: comp reads hsh/bwt/bix only (safe during MFMA);
    //      write touches vt only (between barriers).
    const char* hc = (const char*)hsh;
    auto comp_slot = [&](int kk, int s, unsigned (&res)[8]) {
        int kbase = kk * 81;
        int g = s & 3, p = s >> 2;
        uint2 bw = bwt[kbase + p];
        unsigned ix = bix[kbase + p];
        float w00 = bfhi2f(bw.x << 16), w01 = bfhi2f(bw.x & 0xffff0000u);
        float w10 = bfhi2f(bw.y << 16), w11 = bfhi2f(bw.y & 0xffff0000u);
        unsigned q00 = ix & 255u, q01 = (ix >> 8) & 255u;
        unsigned q10 = (ix >> 16) & 255u, q11 = ix >> 24;
        int b00 = (int)((q00 << 8) | ((q00 & 15u) << 4));
        int b01 = (int)((q01 << 8) | ((q01 & 15u) << 4));
        int b10 = (int)((q10 << 8) | ((q10 & 15u) << 4));
        int b11 = (int)((q11 << 8) | ((q11 & 15u) << 4));
        int gb = g * 64;
#pragma unroll
        for (int jj = 0; jj < 4; ++jj) {
            int off = gb + jj * 16;
            floatx4 a4 = *(const floatx4*)(hc + (b00 ^ off)) * w00;
            a4 += *(const floatx4*)(hc + (b01 ^ off)) * w01;
            a4 += *(const floatx4*)(hc + (b10 ^ off)) * w10;
            a4 += *(const floatx4*)(hc + (b11 ^ off)) * w11;
            unsigned pk0, pk1;
            asm("v_cvt_pk_bf16_f32 %0, %1, %2" : "=v"(pk0) : "v"(a4.x), "v"(a4.y));
            asm("v_cvt_pk_bf16_f32 %0, %1, %2" : "=v"(pk1) : "v"(a4.z), "v"(a4.w));
            res[2 * jj] = pk0; res[2 * jj + 1] = pk1;
        }
    };
    auto write_slot = [&](int s, const unsigned (&res)[8]) {
        int g = s & 3, p = s >> 2;
        int swzv = (p & 7) << 4;
        char* row = vtb + p * 128;
        *(uint4*)(row + ((32 * g) ^ swzv)) = make_uint4(res[0], res[1], res[2], res[3]);
        *(uint4*)(row + ((32 * g + 16) ^ swzv)) = make_uint4(res[4], res[5], res[6], res[7]);
    };

    const bool hasB = t < 68;                 // slots 256..323
    unsigned resA[8], resB[8];
    comp_slot(0, t, resA);
    if (hasB) comp_slot(0, t + 256, resB);

    floatx4 acc[6];
#pragma unroll
    for (int n = 0; n < 6; ++n) acc[n] = (floatx4)0.f;
    int rowb[6], swzn[6];
#pragma unroll
    for (int n = 0; n < 6; ++n) {
        int row = n * 16 + lr; row = row > 80 ? 80 : row;
        rowb[n] = row * 128;
        swzn[n] = (row & 7) << 4;
    }

#pragma unroll
    for (int k = 0; k < 9; ++k) {
        // write-only section (previous tap's reads done via trailing barrier)
        write_slot(t, resA);
        if (hasB) write_slot(t + 256, resB);
        __syncthreads();
        const char* vb = (const char*)vtb;
        // next tap's fill compute overlaps the MFMA section (reads hsh only)
        if (k < 8) { comp_slot(k + 1, t, resA); if (hasB) comp_slot(k + 1, t + 256, resB); }
#pragma unroll
        for (int n = 0; n < 6; ++n) {
            bfrag8 b0 = *(const bfrag8*)(vb + rowb[n] + ((lg * 16) ^ swzn[n]));
            bfrag8 b1 = *(const bfrag8*)(vb + rowb[n] + ((64 + lg * 16) ^ swzn[n]));
            acc[n] = __builtin_amdgcn_mfma_f32_16x16x32_bf16(a[2 * k], b0, acc[n], 0, 0, 0);
            acc[n] = __builtin_amdgcn_mfma_f32_16x16x32_bf16(a[2 * k + 1], b1, acc[n], 0, 0, 0);
        }
        if (k < 8) __syncthreads();
    }

    // ---- epilogue: bias, pre-BN output, BN2 stats (replicated buckets)
    float* outb = dout + OUT_H_BASE + (size_t)b * 5184;
    int bucket = (b & 31) << 6;
#pragma unroll
    for (int j = 0; j < 4; ++j) {
        int oo = wv * 16 + lg * 4 + j;
        float bias = bd[oo];
        float ss = 0.f, qq = 0.f;
#pragma unroll
        for (int n = 0; n < 6; ++n) {
            int p = n * 16 + lr;
            float v = acc[n][j] + bias;
            if (p < 81) { outb[oo * 81 + p] = v; ss += v; qq += v * v; }
        }
#pragma unroll
        for (int off = 1; off < 16; off <<= 1) {
            ss += __shfl_xor(ss, off);
            qq += __shfl_xor(qq, off);
        }
        if (lr == 0) { atomicAdd(&sum2[bucket + oo], ss); atomicAdd(&sq2[bucket + oo], qq); }
    }
}

// ---------------- launch -------------------------------------------------------
extern "C" void kernel_launch(void* const* d_in, const int* in_sizes, int n_in,
                              void* d_out, int out_size, void* d_ws, size_t ws_size,
                              hipStream_t stream) {
    const float* x   = (const float*)d_in[0];
    const float* w1  = (const float*)d_in[1];
    const float* b1  = (const float*)d_in[2];
    const float* g1  = (const float*)d_in[3];
    const float* be1 = (const float*)d_in[4];
    const float* wo  = (const float*)d_in[5];
    const float* bo  = (const float*)d_in[6];
    const float* wm  = (const float*)d_in[7];
    const float* bm  = (const float*)d_in[8];
    const float* wd  = (const float*)d_in[9];
    const float* bd  = (const float*)d_in[10];
    const float* g2  = (const float*)d_in[11];
    const float* be2 = (const float*)d_in[12];
    float* dout = (float*)d_out;
    float* ws   = (float*)d_ws;

    float* h1    = ws + WS_H1;
    float* maskb = ws + WS_MASK;
    const unsigned short* wdt16 = (const unsigned short*)(ws + WS_WDT);
    const unsigned short* w1m   = (const unsigned short*)(ws + WS_W1M);
    const unsigned short* wcm   = (const unsigned short*)(ws + WS_WCM);
    float* stats = ws + WS_STATS;
    float* sum1 = stats,        *sq1 = stats + 2048;
    float* sum2 = stats + 4096, *sq2 = stats + 6144;

    // zero the replicated BN accumulators (ws is NOT re-poisoned between replays)
    hipMemsetAsync(stats, 0, 8192 * sizeof(float), stream);

    prep_weights<<<312, 256, 0, stream>>>(w1, wo, wm, wd, ws);
    conv1_mfma<<<BATCH, 256, 0, stream>>>(x, b1, w1m, h1, sum1, sq1);
    offdeform_mfma<<<BATCH, 256, 0, stream>>>(h1, wcm, wdt16, bo, bm, bd,
                                              sum1, sq1, g1, be1, dout, maskb, sum2, sq2);
    bn_apply2<<<2048, 256, 0, stream>>>(dout + OUT_H_BASE, sum2, sq2, g2, be2,
                                        BATCH * 5184, dout);
}

// Round 15
// 131.791 us; speedup vs baseline: 1.8162x; 1.0569x over previous
//
#include <hip/hip_runtime.h>
#include <hip/hip_bf16.h>

// Problem constants
#define BATCH   2048
#define HW      81          // 9x9
#define CIN     39
#define NPIX    (BATCH*HW)  // 165888

// ws layout (float offsets)
#define WS_H1     0              // 10,616,832 floats  (B,64,81)  PRE-BN h
#define WS_WDT    12109824       // 36,864 ushort bf16 [k][o][c]   (18,432 floats)
#define WS_W1M    12128256       // 24,576 ushort bf16 [12][64][32] (12,288 floats)
#define WS_WCM    12140544       // 18,432 ushort bf16 [18][32][32] (9,216 floats)
#define WS_STATS  12149760       // 8192 floats: sum1[2048],sq1[2048],sum2[2048],sq2[2048]

#define OUT_OFF_BASE 1
#define OUT_H_BASE   (1 + BATCH*18*81)   // 2985985

typedef __attribute__((ext_vector_type(8))) short bfrag8;
typedef __attribute__((ext_vector_type(4))) float floatx4;

__device__ __forceinline__ unsigned short f2bf(float f) {
    unsigned u = __builtin_bit_cast(unsigned, f);
    u += 0x7FFFu + ((u >> 16) & 1u);       // round-to-nearest-even
    return (unsigned short)(u >> 16);
}
__device__ __forceinline__ float bfhi2f(unsigned hi16) {   // hi16 already in bits 31..16
    return __builtin_bit_cast(float, hi16);
}

// ---------------- weight prep: fragment-ready bf16 layouts --------------------
__global__ void prep_weights(const float* __restrict__ w1, const float* __restrict__ wo,
                             const float* __restrict__ wm, const float* __restrict__ wd,
                             float* __restrict__ ws) {
    int idx = blockIdx.x * 256 + threadIdx.x;
    unsigned short* w1m = (unsigned short*)(ws + WS_W1M);
    unsigned short* wcm = (unsigned short*)(ws + WS_WCM);
    unsigned short* wdt16 = (unsigned short*)(ws + WS_WDT);
    if (idx < 24576) {
        int kk = idx & 31, o = (idx >> 5) & 63, s = idx >> 11;
        int tap, c; bool ok = true;
        if (s < 9)       { tap = s;             c = kk; }
        else if (s == 9) { tap = kk >> 3;       c = 32 + (kk & 7); }
        else if (s == 10){ tap = 4 + (kk >> 3); c = 32 + (kk & 7); }
        else             { tap = 8;             c = 32 + (kk & 7); ok = (kk < 8); }
        float v = (ok && c < CIN) ? w1[(o * CIN + c) * 9 + tap] : 0.f;
        w1m[idx] = f2bf(v);
        return;
    }
    int j = idx - 24576;
    if (j >= 0 && j < 18432) {
        int kk = j & 31, oc = (j >> 5) & 31, s = j >> 10;
        int tap = s >> 1, c = (s & 1) * 32 + kk;
        float v = 0.f;
        if (oc < 18)      v = wo[(oc * 64 + c) * 9 + tap];
        else if (oc < 27) v = wm[((oc - 18) * 64 + c) * 9 + tap];
        wcm[j] = f2bf(v);
        return;
    }
    int m = idx - 24576 - 18432;
    if (m >= 0 && m < 36864) {
        int c = m & 63, o = (m >> 6) & 63, k = m >> 12;
        wdt16[m] = f2bf(wd[(o * 64 + c) * 9 + k]);
    }
}

// ---------------- conv1 (39->64) MFMA + ReLU + BN1 stats ----------------------
__global__ __launch_bounds__(256, 4) void conv1_mfma(
        const float* __restrict__ xg, const float* __restrict__ b1,
        const unsigned short* __restrict__ w1m, float* __restrict__ h1,
        float* __restrict__ sum1, float* __restrict__ sq1) {
    __shared__ short xs[128 * 64];   // [r(121)][c(64)] bf16, byte ^= (r&7)<<4
    int b = blockIdx.x, t = threadIdx.x;
    for (int i = t; i < 4096; i += 256) ((unsigned*)xs)[i] = 0u;
    __syncthreads();
    const float* xb = xg + (size_t)b * (HW * CIN);
    const float4* xb4 = (const float4*)xb;
    for (int i4 = t; i4 < 789; i4 += 256) {
        float4 v = xb4[i4];
        float vv[4] = { v.x, v.y, v.z, v.w };
        int base = 4 * i4;
#pragma unroll
        for (int k = 0; k < 4; ++k) {
            int idx = base + k;
            int p = idx / 39, c = idx - 39 * p;
            int y = p / 9, xx = p - 9 * y;
            int r = (y + 1) * 11 + xx + 1;
            int byte = r * 128 + ((c * 2) ^ ((r & 7) << 4));
            xs[byte >> 1] = (short)f2bf(vv[k]);
        }
    }
    if (t < 3) {
        int idx = 3156 + t;
        int p = idx / 39, c = idx - 39 * p;
        int y = p / 9, xx = p - 9 * y;
        int r = (y + 1) * 11 + xx + 1;
        int byte = r * 128 + ((c * 2) ^ ((r & 7) << 4));
        xs[byte >> 1] = (short)f2bf(xb[idx]);
    }
    __syncthreads();
    int lane = t & 63, wv = t >> 6, lg = lane >> 4, lr = lane & 15;
    int o = wv * 16 + lr;
    floatx4 acc[6];
#pragma unroll
    for (int n = 0; n < 6; ++n) acc[n] = (floatx4)0.f;
    int rbn[6];
#pragma unroll
    for (int n = 0; n < 6; ++n) {
        int p = n * 16 + lr; p = p > 80 ? 80 : p;
        int y = p / 9, xx = p - 9 * y;
        rbn[n] = (y + 1) * 11 + xx + 1;
    }
#pragma unroll
    for (int s = 0; s < 12; ++s) {
        bfrag8 a = *(const bfrag8*)&w1m[(s * 64 + o) * 32 + lg * 8];
        int roff, cb;
        if (s < 9)       { roff = (s / 3 - 1) * 11 + (s % 3) - 1; cb = lg * 16; }
        else if (s == 9) { roff = (lg / 3 - 1) * 11 + (lg % 3) - 1; cb = 64; }
        else if (s == 10){ int tp = lg + 4; roff = (tp / 3 - 1) * 11 + (tp % 3) - 1; cb = 64; }
        else             { roff = 12; cb = 64; }
#pragma unroll
        for (int n = 0; n < 6; ++n) {
            int r = rbn[n] + roff;
            int byte = r * 128 + (cb ^ ((r & 7) << 4));
            bfrag8 bf = *(const bfrag8*)((const char*)xs + byte);
            acc[n] = __builtin_amdgcn_mfma_f32_16x16x32_bf16(a, bf, acc[n], 0, 0, 0);
        }
    }
    float* h1b = h1 + (size_t)b * 5184;
    int bucket = (b & 31) << 6;
#pragma unroll
    for (int j = 0; j < 4; ++j) {
        int oo = wv * 16 + lg * 4 + j;
        float bias = b1[oo];
        float ss = 0.f, qq = 0.f;
#pragma unroll
        for (int n = 0; n < 6; ++n) {
            int p = n * 16 + lr;
            float v = fmaxf(acc[n][j] + bias, 0.f);
            if (p < 81) { h1b[oo * 81 + p] = v; ss += v; qq += v * v; }
        }
#pragma unroll
        for (int off = 1; off < 16; off <<= 1) { ss += __shfl_xor(ss, off); qq += __shfl_xor(qq, off); }
        if (lr == 0) { atomicAdd(&sum1[bucket + oo], ss); atomicAdd(&sq1[bucket + oo], qq); }
    }
}

// ---------------- BN2 finalize + apply (fused; aligned float4 body) -----------
__global__ __launch_bounds__(256) void bn_apply2(
        float* __restrict__ data, const float* __restrict__ sums,
        const float* __restrict__ sqs, const float* __restrict__ gamma,
        const float* __restrict__ beta, int n, float* __restrict__ dout) {
    __shared__ float sc[64], sh[64];
    int t = threadIdx.x;
    if (t < 64) {
        float s = 0.f, q = 0.f;
#pragma unroll
        for (int r = 0; r < 32; ++r) { s += sums[(r << 6) + t]; q += sqs[(r << 6) + t]; }
        float m = s / (float)NPIX;
        float v = q / (float)NPIX - m * m;
        float scv = gamma[t] * (1.f / sqrtf(v + 1e-5f));
        sc[t] = scv; sh[t] = beta[t] - m * scv;
    }
    __syncthreads();
    if (blockIdx.x == 0) {
        if (t == 0) dout[0] = 0.5f;
        if (t < 3) data[t] = data[t] * sc[0] + sh[0];   // e<81 -> c=0
        if (t == 3) {
            int e = n - 1;
            int c = (e / 81) & 63;
            data[e] = data[e] * sc[c] + sh[c];
        }
    }
    float4* d4 = (float4*)(data + 3);
    int n4 = (n - 4) >> 2;    // covers elements 3 .. n-2
    for (int i = blockIdx.x * 256 + t; i < n4; i += gridDim.x * 256) {
        float4 v = d4[i];
        unsigned e = 3u + 4u * (unsigned)i;
        int c0 = (int)((e) / 81u) & 63;
        int c1 = (int)((e + 1) / 81u) & 63;
        int c2 = (int)((e + 2) / 81u) & 63;
        int c3 = (int)((e + 3) / 81u) & 63;
        v.x = v.x * sc[c0] + sh[c0];
        v.y = v.y * sc[c1] + sh[c1];
        v.z = v.z * sc[c2] + sh[c2];
        v.w = v.w * sc[c3] + sh[c3];
        d4[i] = v;
    }
}

// ---------------- FUSED offset/mask conv + deformable conv (MFMA) --------------
// r12 structure; offsets/mask stay in LDS between P1 and P2 (no global
// round-trip, no region aliasing): om/omm live in the xs region, which is dead
// after P1's last fragment read (explicit barrier). bwt/bix keep their own
// region. Offsets still go to dout (program output) but are never re-read.
// LDS 40496B -> 4 blocks/CU:
//   hsh [0,20736)      f32 [q][256B], byte q*256 + ((c*4)^((q&15)<<4))
//   bwt [20736,26568)  uint2[729] packed bf16 bilinear weights
//   bix [26568,29484)  uint[729] 4x u8 corner q-indices
//   xs/om/vt [29488,39984) bf16 xs [r(82)][64c] (P0/P1, row 81 zeros);
//                       om f32[1458]+omm f32[729] (P1 epi..P2); vt (fills)
//   sc1/sh1 [39984,40496) BN1 scale/shift
__global__ __launch_bounds__(256, 4) void offdeform_mfma(
        const float* __restrict__ h1, const unsigned short* __restrict__ wcm,
        const unsigned short* __restrict__ wdt16,
        const float* __restrict__ bo, const float* __restrict__ bm,
        const float* __restrict__ bd,
        const float* __restrict__ sum1, const float* __restrict__ sq1,
        const float* __restrict__ g1, const float* __restrict__ be1,
        float* __restrict__ dout, float* __restrict__ sum2, float* __restrict__ sq2) {
    __shared__ __align__(16) char L[40496];
    float*    hsh = (float*)L;
    uint2*    bwt = (uint2*)(L + 20736);
    unsigned* bix = (unsigned*)(L + 26568);
    char*     vtb = L + 29488;               // xs (P0/P1) -> om/omm (P1..P2) -> vt
    float*    om  = (float*)(L + 29488);     // 1458 f32
    float*    omm = (float*)(L + 29488) + 1458; // 729 f32
    float*    sc1 = (float*)(L + 39984);
    float*    sh1 = (float*)(L + 40240);

    int b = blockIdx.x, t = threadIdx.x;
    int lane = t & 63, wv = t >> 6, lg = lane >> 4, lr = lane & 15;

    // ---- BN1 finalize folded in (per block, cheap)
    if (t < 64) {
        float s = 0.f, q = 0.f;
#pragma unroll
        for (int r = 0; r < 32; ++r) { s += sum1[(r << 6) + t]; q += sq1[(r << 6) + t]; }
        float m = s / (float)NPIX;
        float v = q / (float)NPIX - m * m;
        float scv = g1[t] * (1.f / sqrtf(v + 1e-5f));
        sc1[t] = scv; sh1[t] = be1[t] - m * scv;
    }
    __syncthreads();

    // ---- P0: stage h as f32 hsh (swizzled) + bf16 xs (vt layout), BN1 folded
    const float* hb = h1 + (size_t)b * 5184;
    for (int i = t; i < 2592; i += 256) {
        int c2 = i / 81, q = i - c2 * 81;
        int c = 2 * c2;
        float va = hb[c * 81 + q]      * sc1[c]     + sh1[c];
        float vb = hb[c * 81 + 81 + q] * sc1[c + 1] + sh1[c + 1];
        *(float2*)((char*)hsh + q * 256 + ((c * 4) ^ ((q & 15) << 4))) = make_float2(va, vb);
        unsigned pk;
        asm("v_cvt_pk_bf16_f32 %0, %1, %2" : "=v"(pk) : "v"(va), "v"(vb));
        *(unsigned*)(vtb + q * 128 + ((c * 2) ^ ((q & 7) << 4))) = pk;
    }
    if (t < 32) *(unsigned*)(vtb + 81 * 128 + t * 4) = 0u;   // zero row 81
    __syncthreads();

    // ---- P1: offset/mask GEMM; OOB fragments -> zero row (no select)
    int mt = wv >> 1, nh = (wv & 1) * 3;
    int ocr = mt * 16 + lr;
    floatx4 oacc[3];
#pragma unroll
    for (int n = 0; n < 3; ++n) oacc[n] = (floatx4)0.f;
    int yn[3], xn[3];
#pragma unroll
    for (int ni = 0; ni < 3; ++ni) {
        int p = (nh + ni) * 16 + lr; p = p > 80 ? 80 : p;
        yn[ni] = p / 9; xn[ni] = p - 9 * yn[ni];
    }
#pragma unroll
    for (int s = 0; s < 18; ++s) {
        const int tap = s >> 1, dyk = tap / 3 - 1, dxk = tap % 3 - 1;
        const int cb1 = (s & 1) * 64 + lg * 16;
        bfrag8 af = *(const bfrag8*)&wcm[(s * 32 + ocr) * 32 + lg * 8];
#pragma unroll
        for (int ni = 0; ni < 3; ++ni) {
            int yy = yn[ni] + dyk, xx2 = xn[ni] + dxk;
            bool val = ((unsigned)yy < 9u) & ((unsigned)xx2 < 9u);
            int q2 = val ? yy * 9 + xx2 : 81;
            bfrag8 bf = *(const bfrag8*)(vtb + q2 * 128 + (cb1 ^ ((q2 & 7) << 4)));
            oacc[ni] = __builtin_amdgcn_mfma_f32_16x16x32_bf16(af, bf, oacc[ni], 0, 0, 0);
        }
    }
    __syncthreads();   // ALL waves done reading xs before om/omm overwrite it

    // P1 epilogue: offsets -> dout (output) + om (LDS); mask -> omm (LDS)
#pragma unroll
    for (int j = 0; j < 4; ++j) {
        int oc = mt * 16 + lg * 4 + j;
        if (oc < 18) {
            float bias = bo[oc];
            float* ob = dout + OUT_OFF_BASE + (size_t)b * 1458 + oc * 81;
#pragma unroll
            for (int ni = 0; ni < 3; ++ni) {
                int p = (nh + ni) * 16 + lr;
                if (p < 81) { float v = oacc[ni][j] + bias; ob[p] = v; om[oc * 81 + p] = v; }
            }
        } else if (oc < 27) {
            float bias = bm[oc - 18];
#pragma unroll
            for (int ni = 0; ni < 3; ++ni) {
                int p = (nh + ni) * 16 + lr;
                if (p < 81) { float v = oacc[ni][j] + bias; omm[(oc - 18) * 81 + p] = 1.f / (1.f + expf(-v)); }
            }
        }
    }
    __syncthreads();   // om/omm visible to all waves

    // ---- deform A fragments (L2-hot; latency hides under P2)
    int o = wv * 16 + lr;
    bfrag8 a[18];
#pragma unroll
    for (int s = 0; s < 18; ++s) {
        int k = s >> 1, ks = s & 1;
        a[s] = *(const bfrag8*)&wdt16[(k * 64 + o) * 64 + ks * 32 + lg * 8];
    }

    // ---- P2: bilinear params per (tap,pixel) from LDS om/omm -> bwt/bix
    for (int i = t; i < 729; i += 256) {
        int k = i / 81, p = i - k * 81;
        float dy = om[(2 * k) * 81 + p];
        float dx = om[(2 * k + 1) * 81 + p];
        float m  = omm[i];
        int y = p / 9, xx = p - y * 9;
        float py = dy + (float)(y + k / 3 - 1);
        float px = dx + (float)(xx + (k % 3) - 1);
        float fy = floorf(py), fx = floorf(px);
        float ly = py - fy, lx = px - fx;
        int y0 = (int)fy, x0 = (int)fx;
        int y1 = y0 + 1, x1 = x0 + 1;
        bool vy0 = (y0 >= 0) & (y0 < 9), vy1 = (y1 >= 0) & (y1 < 9);
        bool vx0 = (x0 >= 0) & (x0 < 9), vx1 = (x1 >= 0) & (x1 < 9);
        float w00 = (vy0 && vx0) ? m * (1.f - ly) * (1.f - lx) : 0.f;
        float w01 = (vy0 && vx1) ? m * (1.f - ly) * lx : 0.f;
        float w10 = (vy1 && vx0) ? m * ly * (1.f - lx) : 0.f;
        float w11 = (vy1 && vx1) ? m * ly * lx : 0.f;
        int yc0 = min(max(y0, 0), 8), yc1 = min(max(y1, 0), 8);
        int xc0 = min(max(x0, 0), 8), xc1 = min(max(x1, 0), 8);
        unsigned q00 = yc0 * 9 + xc0, q01 = yc0 * 9 + xc1;
        unsigned q10 = yc1 * 9 + xc0, q11 = yc1 * 9 + xc1;
        bwt[i] = make_uint2((unsigned)f2bf(w00) | ((unsigned)f2bf(w01) << 16),
                            (unsigned)f2bf(w10) | ((unsigned)f2bf(w11) << 16));
        bix[i] = q00 | (q01 << 8) | (q10 << 16) | (q11 << 24);
    }
    __syncthreads();   // params visible; om/omm dead; vt region free for fills

    // ---- fill tap kk into vt: 324 slots = (81 p) x (4 c-octets), b128 reads
    auto stage_tap = [&](int kk) {
        int kbase = kk * 81;
        const char* hc = (const char*)hsh;
#pragma unroll
        for (int j2 = 0; j2 < 2; ++j2) {
            int s = t + j2 * 256;
            if (j2 == 1 && s >= 324) break;
            int g = s & 3, p = s >> 2;
            uint2 bw = bwt[kbase + p];
            unsigned ix = bix[kbase + p];
            float w00 = bfhi2f(bw.x << 16), w01 = bfhi2f(bw.x & 0xffff0000u);
            float w10 = bfhi2f(bw.y << 16), w11 = bfhi2f(bw.y & 0xffff0000u);
            unsigned q00 = ix & 255u, q01 = (ix >> 8) & 255u;
            unsigned q10 = (ix >> 16) & 255u, q11 = ix >> 24;
            int b00 = (int)((q00 << 8) | ((q00 & 15u) << 4));
            int b01 = (int)((q01 << 8) | ((q01 & 15u) << 4));
            int b10 = (int)((q10 << 8) | ((q10 & 15u) << 4));
            int b11 = (int)((q11 << 8) | ((q11 & 15u) << 4));
            int gb = g * 64;
            unsigned res[8];
#pragma unroll
            for (int jj = 0; jj < 4; ++jj) {
                int off = gb + jj * 16;
                floatx4 a4 = *(const floatx4*)(hc + (b00 ^ off)) * w00;
                a4 += *(const floatx4*)(hc + (b01 ^ off)) * w01;
                a4 += *(const floatx4*)(hc + (b10 ^ off)) * w10;
                a4 += *(const floatx4*)(hc + (b11 ^ off)) * w11;
                unsigned pk0, pk1;
                asm("v_cvt_pk_bf16_f32 %0, %1, %2" : "=v"(pk0) : "v"(a4.x), "v"(a4.y));
                asm("v_cvt_pk_bf16_f32 %0, %1, %2" : "=v"(pk1) : "v"(a4.z), "v"(a4.w));
                res[2 * jj] = pk0; res[2 * jj + 1] = pk1;
            }
            int swzv = (p & 7) << 4;
            char* row = vtb + p * 128;
            *(uint4*)(row + ((32 * g) ^ swzv)) = make_uint4(res[0], res[1], res[2], res[3]);
            *(uint4*)(row + ((32 * g + 16) ^ swzv)) = make_uint4(res[4], res[5], res[6], res[7]);
        }
    };

    floatx4 acc[6];
#pragma unroll
    for (int n = 0; n < 6; ++n) acc[n] = (floatx4)0.f;
    int rowb[6], swzn[6];
#pragma unroll
    for (int n = 0; n < 6; ++n) {
        int row = n * 16 + lr; row = row > 80 ? 80 : row;
        rowb[n] = row * 128;
        swzn[n] = (row & 7) << 4;
    }

#pragma unroll
    for (int k = 0; k < 9; ++k) {
        stage_tap(k);
        __syncthreads();
        const char* vb = (const char*)vtb;
#pragma unroll
        for (int n = 0; n < 6; ++n) {
            bfrag8 b0 = *(const bfrag8*)(vb + rowb[n] + ((lg * 16) ^ swzn[n]));
            bfrag8 b1 = *(const bfrag8*)(vb + rowb[n] + ((64 + lg * 16) ^ swzn[n]));
            acc[n] = __builtin_amdgcn_mfma_f32_16x16x32_bf16(a[2 * k], b0, acc[n], 0, 0, 0);
            acc[n] = __builtin_amdgcn_mfma_f32_16x16x32_bf16(a[2 * k + 1], b1, acc[n], 0, 0, 0);
        }
        if (k < 8) __syncthreads();
    }

    // ---- epilogue: bias, pre-BN output, BN2 stats (replicated buckets)
    float* outb = dout + OUT_H_BASE + (size_t)b * 5184;
    int bucket = (b & 31) << 6;
#pragma unroll
    for (int j = 0; j < 4; ++j) {
        int oo = wv * 16 + lg * 4 + j;
        float bias = bd[oo];
        float ss = 0.f, qq = 0.f;
#pragma unroll
        for (int n = 0; n < 6; ++n) {
            int p = n * 16 + lr;
            float v = acc[n][j] + bias;
            if (p < 81) { outb[oo * 81 + p] = v; ss += v; qq += v * v; }
        }
#pragma unroll
        for (int off = 1; off < 16; off <<= 1) {
            ss += __shfl_xor(ss, off);
            qq += __shfl_xor(qq, off);
        }
        if (lr == 0) { atomicAdd(&sum2[bucket + oo], ss); atomicAdd(&sq2[bucket + oo], qq); }
    }
}

// ---------------- launch -------------------------------------------------------
extern "C" void kernel_launch(void* const* d_in, const int* in_sizes, int n_in,
                              void* d_out, int out_size, void* d_ws, size_t ws_size,
                              hipStream_t stream) {
    const float* x   = (const float*)d_in[0];
    const float* w1  = (const float*)d_in[1];
    const float* b1  = (const float*)d_in[2];
    const float* g1  = (const float*)d_in[3];
    const float* be1 = (const float*)d_in[4];
    const float* wo  = (const float*)d_in[5];
    const float* bo  = (const float*)d_in[6];
    const float* wm  = (const float*)d_in[7];
    const float* bm  = (const float*)d_in[8];
    const float* wd  = (const float*)d_in[9];
    const float* bd  = (const float*)d_in[10];
    const float* g2  = (const float*)d_in[11];
    const float* be2 = (const float*)d_in[12];
    float* dout = (float*)d_out;
    float* ws   = (float*)d_ws;

    float* h1    = ws + WS_H1;
    const unsigned short* wdt16 = (const unsigned short*)(ws + WS_WDT);
    const unsigned short* w1m   = (const unsigned short*)(ws + WS_W1M);
    const unsigned short* wcm   = (const unsigned short*)(ws + WS_WCM);
    float* stats = ws + WS_STATS;
    float* sum1 = stats,        *sq1 = stats + 2048;
    float* sum2 = stats + 4096, *sq2 = stats + 6144;

    // zero the replicated BN accumulators (ws is NOT re-poisoned between replays)
    hipMemsetAsync(stats, 0, 8192 * sizeof(float), stream);

    prep_weights<<<312, 256, 0, stream>>>(w1, wo, wm, wd, ws);
    conv1_mfma<<<BATCH, 256, 0, stream>>>(x, b1, w1m, h1, sum1, sq1);
    offdeform_mfma<<<BATCH, 256, 0, stream>>>(h1, wcm, wdt16, bo, bm, bd,
                                              sum1, sq1, g1, be1, dout, sum2, sq2);
    bn_apply2<<<2048, 256, 0, stream>>>(dout + OUT_H_BASE, sum2, sq2, g2, be2,
                                        BATCH * 5184, dout);
}